// Round 14
// baseline (74.941 us; speedup 1.0000x reference)
//
#include <hip/hip_runtime.h>

#define HD 257
#define WD 257
#define NB (8 * HD)    // 2056 (b,y)-row buckets
#define NCHUNK 32      // chunks per batch
#define CAPC 32        // per-(bucket,chunk) slot capacity (lambda~4 -> safe)
#define BPTS 1024      // bin: points per block
#define COUT 64
#define LROW 17        // accum LDS row stride (floats): breaks x*16 bank pattern
#define RPB 2          // accum: rows per block
#define DCAP 448       // gather dense-list capacity (lambda~128; overflow impossible)
#define ROWW 259       // staged row cells: 1 zero-guard + 257 + 1 zero-guard
// row bytes = ROWW*32 = 8288; uint4 elems per row = 518

typedef unsigned int uint;
typedef unsigned short ushort;
typedef short short8 __attribute__((ext_vector_type(8)));
typedef float f32x4 __attribute__((ext_vector_type(4)));

// f32 -> bf16 RNE
__device__ __forceinline__ uint pack_bf16(float a, float b) {
    uint ua = __float_as_uint(a), ub = __float_as_uint(b);
    ua += 0x7fffu + ((ua >> 16) & 1u);
    ub += 0x7fffu + ((ub >> 16) & 1u);
    return (ua >> 16) | (ub & 0xffff0000u);
}
__device__ __forceinline__ unsigned short bf16_1(float a) {
    uint ua = __float_as_uint(a);
    ua += 0x7fffu + ((ua >> 16) & 1u);
    return (unsigned short)(ua >> 16);
}

// K1: bin — NO global atomics. Block (chunk,b): LDS histogram of its 1024
// points; chunk-local ranks; plain stores of cnt2 + packed (x<<16 | lp).
__global__ __launch_bounds__(256) void bin_kernel(
    const float* __restrict__ xyzp,
    uint* __restrict__ cnt2,     // [NB][NCHUNK]
    uint* __restrict__ pidx,     // [NB][NCHUNK][CAPC]  (x<<16 | local point idx)
    int N) {
    __shared__ uint hist[HD];
    const int tid = threadIdx.x;
    const int chunk = blockIdx.x;
    const int b = blockIdx.y;
    const int p0 = chunk * BPTS;
    for (int i = tid; i < HD; i += 256) hist[i] = 0u;
    __syncthreads();

    const float4* xp = reinterpret_cast<const float4*>(xyzp) + (size_t)b * N;
    uint rec[BPTS / 256], xrec[BPTS / 256];
#pragma unroll
    for (int k = 0; k < BPTS / 256; ++k) {
        int i = p0 + tid + k * 256;
        float4 v = xp[i];
        int y = (int)fminf(fmaxf(rintf(v.y * 256.0f), 0.0f), 256.0f);
        int x = (int)fminf(fmaxf(rintf(v.x * 256.0f), 0.0f), 256.0f);
        uint r = atomicAdd(&hist[y], 1u);   // LDS only
        rec[k] = (uint)y | (r << 9);
        xrec[k] = (uint)x;
    }
    __syncthreads();

    for (int y = tid; y < HD; y += 256)
        cnt2[(size_t)(b * HD + y) * NCHUNK + chunk] = min(hist[y], (uint)CAPC);

#pragma unroll
    for (int k = 0; k < BPTS / 256; ++k) {
        int y = rec[k] & 511;
        uint r = rec[k] >> 9;
        if (r < CAPC)
            pidx[((size_t)(b * HD + y) * NCHUNK + chunk) * CAPC + r] =
                (xrec[k] << 16) | (uint)(p0 + tid + k * 256);
    }
}

// K2: accum — RPB rows/block; predicated slot-grid loop; x from bin payload
// (no xyzp float4 read; w is a scalar load); f32 LDS accumulate; normalize
// (count = ch0+ch1); emit bf16 voxel rows.
__global__ __launch_bounds__(256) void accum_kernel(
    const uint* __restrict__ cnt2,
    const uint* __restrict__ pidx,
    const float* __restrict__ xyzp,
    const float* __restrict__ feat,
    uint* __restrict__ voxn,       // [S][8] normalized bf16 pairs
    int logN) {
    __shared__ float l[RPB * WD * LROW];   // 34952 B
    __shared__ uint pc[RPB * NCHUNK];      // 64 chunk counts
    const int tid = threadIdx.x;
    const int bucket0 = blockIdx.x * RPB;
    for (int i = tid; i < RPB * WD * LROW; i += 256) l[i] = 0.0f;
    if (tid < RPB * NCHUNK)
        pc[tid] = cnt2[(size_t)bucket0 * NCHUNK + tid];
    __syncthreads();

#pragma unroll
    for (int s = 0; s < RPB * NCHUNK * CAPC; s += 256) {
        int slot = s + tid;
        int c = slot >> 5;              // (row,chunk) index: CAPC=32
        int j = slot & (CAPC - 1);
        if ((uint)j < pc[c]) {          // predicated: ~12.5% density
            int r = c >> 5;             // NCHUNK=32
            int chunk = c & 31;
            int bucket = bucket0 + r;
            int b = bucket / HD;        // const-div -> magic mul
            uint e = pidx[((size_t)bucket * NCHUNK + chunk) * CAPC + j];
            int x = (int)(e >> 16);
            int p = (b << logN) + (int)(e & 0xffffu);
            float w = xyzp[(size_t)p * 4 + 3];
            float* cell = l + (r * WD + x) * LROW;
            atomicAdd(&cell[0], w);
            atomicAdd(&cell[1], 1.0f - w);
            const float2* f2 = reinterpret_cast<const float2*>(feat + (size_t)p * 14);
#pragma unroll
            for (int jj = 0; jj < 7; ++jj) {
                float2 fv = f2[jj];
                atomicAdd(&cell[2 + 2 * jj], fv.x);
                atomicAdd(&cell[3 + 2 * jj], fv.y);
            }
        }
    }
    __syncthreads();

    for (int i = tid; i < RPB * WD; i += 256) {
        int r = i / WD;
        int x = i - r * WD;
        const float* c = l + (r * WD + x) * LROW;
        float inv = __builtin_amdgcn_rcpf(fmaxf(c[0] + c[1], 1.0f));
        uint o[8];
#pragma unroll
        for (int j = 0; j < 8; ++j)
            o[j] = pack_bf16(c[2 * j] * inv, c[2 * j + 1] * inv);
        uint4* op = reinterpret_cast<uint4*>(voxn + ((size_t)(bucket0 + r) * WD + x) * 8);
        op[0] = make_uint4(o[0], o[1], o[2], o[3]);
        op[1] = make_uint4(o[4], o[5], o[6], o[7]);
    }
}

// K3: gather-v4 — bucket-ordered. One block per (b,y) bucket: stage rows
// y-1,y,y+1 coalesced into LDS (+-1 zero-guard cells), build dense point list
// from pidx, then MFMA 64-point tiles with A-fragments read straight from the
// row LDS. Lane cell index = x + kx (kx absorbs the guard shift — NO extra +1;
// round-13 bug was double-counting it). Zero scattered global loads.
__global__ __launch_bounds__(256) void gather_mfma_kernel(
    const uint* __restrict__ cnt2,
    const uint* __restrict__ pidx,
    const uint* __restrict__ voxn,   // [S][8] normalized bf16 pairs
    const float* __restrict__ W,     // [9][16][64] f32 = [144][64]
    const float* __restrict__ bias,
    float* __restrict__ out, int logN) {
    __shared__ __align__(16) uint4 sRows[3 * 518];   // 24864 B
    __shared__ uint sPC[NCHUNK], sBase[NCHUNK];
    __shared__ uint sNtot;
    __shared__ ushort sPid[DCAP], sXv[DCAP];         // 1792 B

    const int tid = threadIdx.x;
    const int lane = tid & 63;
    const int w = tid >> 6;
    const int hi = lane >> 4;
    const int lo = lane & 15;
    const int bucket = blockIdx.x;
    const int b = bucket / HD;
    const int y = bucket - b * HD;

    if (tid < NCHUNK) sPC[tid] = cnt2[(size_t)bucket * NCHUNK + tid];
    __syncthreads();

    // phase 1: prefix (thread 0) || pad dense arrays || stage 3 voxel rows
    if (tid == 0) {
        uint a = 0;
#pragma unroll
        for (int c = 0; c < NCHUNK; ++c) { sBase[c] = a; a += sPC[c]; }
        sNtot = min(a, (uint)DCAP);
    }
    for (int i = tid; i < DCAP; i += 256) { sPid[i] = 0xffffu; sXv[i] = 0; }
    for (int idx = tid; idx < 3 * 518; idx += 256) {
        int seg = idx / 518;
        int rem = idx - seg * 518;
        int cellx = rem >> 1, half = rem & 1;
        int ny = y + seg - 1;
        int nx = cellx - 1;
        uint4 val = make_uint4(0, 0, 0, 0);
        if ((uint)ny <= 256u && (uint)nx <= 256u)
            val = reinterpret_cast<const uint4*>(voxn)
                      [((size_t)(b * HD + ny) * WD + nx) * 2 + half];
        sRows[idx] = val;
    }

    // B fragments (global, L2-hot) + bias
    short8 bfrag[5];
    float bv = bias[w * 16 + lo];
#pragma unroll
    for (int s = 0; s < 5; ++s) {
        int kbase = s * 32 + hi * 8;
        short8 f;
#pragma unroll
        for (int j = 0; j < 8; ++j) {
            int k = kbase + j;
            float wv = (k < 144) ? W[(size_t)k * 64 + w * 16 + lo] : 0.0f;
            f[j] = (short)bf16_1(wv);
        }
        bfrag[s] = f;
    }
    __syncthreads();

    // phase 2: dense copy (needs sBase + pad)
    for (int idx = tid; idx < NCHUNK * CAPC; idx += 256) {
        int c = idx >> 5, j = idx & (CAPC - 1);
        if ((uint)j < sPC[c]) {
            uint e = pidx[((size_t)bucket * NCHUNK + c) * CAPC + j];
            uint pos = sBase[c] + j;
            if (pos < DCAP) {
                sPid[pos] = (ushort)(e & 0xffffu);
                sXv[pos] = (ushort)(e >> 16);    // cell index = x + kx (kx has the +1)
            }
        }
    }
    __syncthreads();

    // per-lane constant A offsets: k = s*32 + hi*8 + j -> kn = 2s + (hi>>1),
    // byte = seg*8288 + kx*32 + (hi&1)*16 with seg=kn/3, kx=kn%3.
    const int hh = hi >> 1, hl = hi & 1;
    int offA[5];
#pragma unroll
    for (int s = 0; s < 5; ++s) {
        int kn = 2 * s + hh;          // 0..9; 9 == zero-pad
        int kc = (kn > 8) ? 0 : kn;   // clamp; s==4&&hh==1 handled below
        int seg = (kc * 11) >> 5;     // /3 for 0..8
        int kx = kc - 3 * seg;
        offA[s] = seg * 8288 + kx * 32 + hl * 16;
    }
    const bool s4ok = (hh == 0);
    const char* rowsB = reinterpret_cast<const char*>(sRows);

    const uint ntile = (sNtot + 63u) >> 6;
    for (uint t = 0; t < ntile; ++t) {
        int base = (int)t * 64;
        f32x4 acc[4];
#pragma unroll
        for (int mt = 0; mt < 4; ++mt) acc[mt] = (f32x4){bv, bv, bv, bv};

#pragma unroll
        for (int mt = 0; mt < 4; ++mt) {
            int xb = (int)sXv[base + mt * 16 + lo] << 5;   // x byte offset
#pragma unroll
            for (int s = 0; s < 5; ++s) {
                int addr = offA[s] + xb;
                if (s == 4 && !s4ok) addr = 0;   // k in [144,160): guard cell 0 = zeros
                short8 a = *reinterpret_cast<const short8*>(rowsB + addr);
                acc[mt] = __builtin_amdgcn_mfma_f32_16x16x32_bf16(a, bfrag[s], acc[mt], 0, 0, 0);
            }
        }

        // store: D col = lane&15, row = hi*4 + reg (m89-verified)
#pragma unroll
        for (int mt = 0; mt < 4; ++mt)
#pragma unroll
            for (int r = 0; r < 4; ++r) {
                uint pid = sPid[base + mt * 16 + hi * 4 + r];
                if (pid != 0xffffu) {
                    size_t p = ((size_t)b << logN) + pid;
                    out[p * 64 + w * 16 + lo] = acc[mt][r];
                }
            }
    }
}

extern "C" void kernel_launch(void* const* d_in, const int* in_sizes, int n_in,
                              void* d_out, int out_size, void* d_ws, size_t ws_size,
                              hipStream_t stream) {
    const float* xyzp = (const float*)d_in[0];
    const float* feat = (const float*)d_in[1];
    const float* W    = (const float*)d_in[2];
    const float* bias = (const float*)d_in[3];
    float* out = (float*)d_out;

    const int BN = in_sizes[0] / 4;  // 262144
    const int B = 8;
    const int N = BN / B;            // 32768
    int logN = 0;
    while ((1 << logN) < N) ++logN;  // 15

    // ws layout: cnt2 | pidx(u32) | voxn  ~= 25.6 MB
    uint* cnt2 = (uint*)d_ws;                                        // 263168 B
    uint* pidx = (uint*)((char*)cnt2 + (size_t)NB * NCHUNK * 4);     // 8.42 MB
    uint* voxn = (uint*)((char*)pidx + (size_t)NB * NCHUNK * CAPC * 4);  // 16.9 MB
    (void)ws_size;

    dim3 bgrid(NCHUNK, B);           // 32 x 8
    bin_kernel<<<bgrid, 256, 0, stream>>>(xyzp, cnt2, pidx, N);
    accum_kernel<<<NB / RPB, 256, 0, stream>>>(cnt2, pidx, xyzp, feat, voxn, logN);
    gather_mfma_kernel<<<NB, 256, 0, stream>>>(cnt2, pidx, voxn, W, bias, out, logN);
}

// Round 15
// 67.012 us; speedup vs baseline: 1.1183x; 1.1183x over previous
//
#include <hip/hip_runtime.h>

#define HD 257
#define WD 257
#define NB (8 * HD)    // 2056 (b,y)-row buckets
#define NCHUNK 32      // chunks per batch
#define CAPC 32        // per-(bucket,chunk) slot capacity (lambda~4 -> safe)
#define BPTS 1024      // bin: points per block
#define COUT 64
#define LROW 17        // accum LDS row stride (floats): breaks x*16 bank pattern
#define GPTS 64        // gather: points per block

typedef unsigned int uint;
typedef unsigned short ushort;
typedef short short8 __attribute__((ext_vector_type(8)));
typedef float f32x4 __attribute__((ext_vector_type(4)));

// f32 -> bf16 RNE
__device__ __forceinline__ uint pack_bf16(float a, float b) {
    uint ua = __float_as_uint(a), ub = __float_as_uint(b);
    ua += 0x7fffu + ((ua >> 16) & 1u);
    ub += 0x7fffu + ((ub >> 16) & 1u);
    return (ua >> 16) | (ub & 0xffff0000u);
}
__device__ __forceinline__ unsigned short bf16_1(float a) {
    uint ua = __float_as_uint(a);
    ua += 0x7fffu + ((ua >> 16) & 1u);
    return (unsigned short)(ua >> 16);
}

// K1: bin — NO global atomics, no zero pass. Block (chunk,b): LDS histogram
// of its 1024 points, chunk-local ranks, plain stores of cnt2 + pidx.
__global__ __launch_bounds__(256) void bin_kernel(
    const float* __restrict__ xyzp,
    uint* __restrict__ cnt2,     // [NB][NCHUNK]
    ushort* __restrict__ pidx,   // [NB][NCHUNK][CAPC] local point idx in batch
    int N) {
    __shared__ uint hist[HD];
    const int tid = threadIdx.x;
    const int chunk = blockIdx.x;
    const int b = blockIdx.y;
    const int p0 = chunk * BPTS;
    for (int i = tid; i < HD; i += 256) hist[i] = 0u;
    __syncthreads();

    const float4* xp = reinterpret_cast<const float4*>(xyzp) + (size_t)b * N;
    uint rec[BPTS / 256];
#pragma unroll
    for (int k = 0; k < BPTS / 256; ++k) {
        int i = p0 + tid + k * 256;
        float4 v = xp[i];
        int y = (int)fminf(fmaxf(rintf(v.y * 256.0f), 0.0f), 256.0f);
        uint r = atomicAdd(&hist[y], 1u);   // LDS only
        rec[k] = (uint)y | (r << 9);
    }
    __syncthreads();

    for (int y = tid; y < HD; y += 256)
        cnt2[(size_t)(b * HD + y) * NCHUNK + chunk] = min(hist[y], (uint)CAPC);

#pragma unroll
    for (int k = 0; k < BPTS / 256; ++k) {
        int y = rec[k] & 511;
        uint r = rec[k] >> 9;
        if (r < CAPC)
            pidx[((size_t)(b * HD + y) * NCHUNK + chunk) * CAPC + r] =
                (ushort)(p0 + tid + k * 256);
    }
}

// K2: accum — RPB=1: one row bucket per block (2056 blocks, 17.5 KB LDS ->
// 8 blocks/CU, 2x the resident waves of RPB=2). Predicated slot-grid loop
// (1024 slots, 4 strided steps); f32 LDS accumulate; normalize (count =
// ch0+ch1); emit bf16 voxel rows.
__global__ __launch_bounds__(256) void accum_kernel(
    const uint* __restrict__ cnt2,
    const ushort* __restrict__ pidx,
    const float* __restrict__ xyzp,
    const float* __restrict__ feat,
    uint* __restrict__ voxn,       // [S][8] normalized bf16 pairs
    int logN) {
    __shared__ float l[WD * LROW];   // 17476 B -> 8 blocks/CU
    __shared__ uint pc[NCHUNK];      // 32 chunk counts
    const int tid = threadIdx.x;
    const int bucket = blockIdx.x;
    const int b = bucket / HD;       // const-div -> magic mul
    for (int i = tid; i < WD * LROW; i += 256) l[i] = 0.0f;
    if (tid < NCHUNK)
        pc[tid] = cnt2[(size_t)bucket * NCHUNK + tid];
    __syncthreads();

#pragma unroll
    for (int s = 0; s < NCHUNK * CAPC; s += 256) {
        int slot = s + tid;
        int c = slot >> 5;              // chunk: CAPC=32
        int j = slot & (CAPC - 1);
        if ((uint)j < pc[c]) {          // predicated: ~12.5% density
            uint lp = pidx[((size_t)bucket * NCHUNK + c) * CAPC + j];
            int p = (b << logN) + (int)lp;
            float4 v = reinterpret_cast<const float4*>(xyzp)[p];
            int x = (int)fminf(fmaxf(rintf(v.x * 256.0f), 0.0f), 256.0f);
            float* cell = l + x * LROW;
            atomicAdd(&cell[0], v.w);
            atomicAdd(&cell[1], 1.0f - v.w);
            const float2* f2 = reinterpret_cast<const float2*>(feat + (size_t)p * 14);
#pragma unroll
            for (int jj = 0; jj < 7; ++jj) {
                float2 fv = f2[jj];
                atomicAdd(&cell[2 + 2 * jj], fv.x);
                atomicAdd(&cell[3 + 2 * jj], fv.y);
            }
        }
    }
    __syncthreads();

    for (int x = tid; x < WD; x += 256) {
        const float* c = l + x * LROW;
        float inv = __builtin_amdgcn_rcpf(fmaxf(c[0] + c[1], 1.0f));
        uint o[8];
#pragma unroll
        for (int j = 0; j < 8; ++j)
            o[j] = pack_bf16(c[2 * j] * inv, c[2 * j + 1] * inv);
        uint4* op = reinterpret_cast<uint4*>(voxn + ((size_t)bucket * WD + x) * 8);
        op[0] = make_uint4(o[0], o[1], o[2], o[3]);
        op[1] = make_uint4(o[4], o[5], o[6], o[7]);
    }
}

// K3: 64 points / 256 thr (4 waves). A[64][K=160] bf16 in LDS (336 B row).
// Wave w computes cols w*16..w*16+15 over all 64 rows. k = (dy*3+dx)*16 + c.
__global__ __launch_bounds__(256) void gather_mfma_kernel(
    const float* __restrict__ xyzp,
    const uint* __restrict__ voxn,   // [S][8] normalized bf16 pairs
    const float* __restrict__ W,     // [9][16][64] f32 = [144][64]
    const float* __restrict__ bias,
    float* __restrict__ out, int logN) {
    __shared__ __align__(16) char sA[GPTS * 336];  // 21504 B
    __shared__ int sCell[GPTS];
    __shared__ uint sYX[GPTS];

    const int tid = threadIdx.x;
    const int lane = tid & 63;
    const int w = tid >> 6;
    const int p0 = blockIdx.x * GPTS;
    const int hi = lane >> 4;
    const int lo = lane & 15;

    // per-point data computed ONCE (threads 0..63)
    if (tid < GPTS) {
        float4 v = reinterpret_cast<const float4*>(xyzp)[p0 + tid];
        int y = (int)fminf(fmaxf(rintf(v.y * 256.0f), 0.0f), 256.0f);
        int x = (int)fminf(fmaxf(rintf(v.x * 256.0f), 0.0f), 256.0f);
        int b = (p0 + tid) >> logN;
        sCell[tid] = (b * HD + y) * WD + x;
        sYX[tid] = ((uint)y << 16) | (uint)x;
    }

    // B fragments (issued before barrier; latency overlaps)
    short8 bfrag[5];
    float bv = bias[w * 16 + lo];
#pragma unroll
    for (int s = 0; s < 5; ++s) {
        int kbase = s * 32 + hi * 8;
        short8 f;
#pragma unroll
        for (int j = 0; j < 8; ++j) {
            int k = kbase + j;
            float wv = (k < 144) ? W[(size_t)k * 64 + w * 16 + lo] : 0.0f;
            f[j] = (short)bf16_1(wv);
        }
        bfrag[s] = f;
    }
    __syncthreads();

    // A build: 18 chunks/point (3 dy-segs x 3 kx x 2 halves of 16 B)
    for (int idx = tid; idx < GPTS * 18; idx += 256) {
        int i = idx / 18;
        int r = idx - i * 18;
        int seg = r / 6;          // dy+1
        int h = r - seg * 6;
        int kx = h >> 1;
        int half = h & 1;
        uint yx = sYX[i];
        int y = (int)(yx >> 16), x = (int)(yx & 0xffffu);
        int ny = y + seg - 1, nx = x + kx - 1;
        uint4 val = make_uint4(0, 0, 0, 0);
        if ((uint)ny <= 256u && (uint)nx <= 256u) {
            size_t ncell = (size_t)sCell[i] + (size_t)((seg - 1) * WD + (kx - 1));
            val = *reinterpret_cast<const uint4*>(
                reinterpret_cast<const char*>(voxn) + ncell * 32 + (size_t)half * 16);
        }
        *reinterpret_cast<uint4*>(sA + i * 336 + (seg * 3 + kx) * 32 + half * 16) = val;
    }
    // zero-pad k in [144,160)
    if (tid < GPTS * 2) {
        int i = tid >> 1, h = tid & 1;
        *reinterpret_cast<uint4*>(sA + i * 336 + 288 + h * 16) = make_uint4(0, 0, 0, 0);
    }
    __syncthreads();

    f32x4 acc[4];
#pragma unroll
    for (int mt = 0; mt < 4; ++mt) acc[mt] = (f32x4){bv, bv, bv, bv};

#pragma unroll
    for (int mt = 0; mt < 4; ++mt) {
        const char* abase = sA + (mt * 16 + lo) * 336 + hi * 16;
#pragma unroll
        for (int s = 0; s < 5; ++s) {
            short8 a = *reinterpret_cast<const short8*>(abase + s * 64);
            acc[mt] = __builtin_amdgcn_mfma_f32_16x16x32_bf16(a, bfrag[s], acc[mt], 0, 0, 0);
        }
    }

    // store: D col = lane&15, row = hi*4 + reg (m89-verified)
#pragma unroll
    for (int mt = 0; mt < 4; ++mt)
#pragma unroll
        for (int r = 0; r < 4; ++r) {
            int row = mt * 16 + hi * 4 + r;
            out[(size_t)(p0 + row) * 64 + w * 16 + lo] = acc[mt][r];
        }
}

extern "C" void kernel_launch(void* const* d_in, const int* in_sizes, int n_in,
                              void* d_out, int out_size, void* d_ws, size_t ws_size,
                              hipStream_t stream) {
    const float* xyzp = (const float*)d_in[0];
    const float* feat = (const float*)d_in[1];
    const float* W    = (const float*)d_in[2];
    const float* bias = (const float*)d_in[3];
    float* out = (float*)d_out;

    const int BN = in_sizes[0] / 4;  // 262144
    const int B = 8;
    const int N = BN / B;            // 32768
    int logN = 0;
    while ((1 << logN) < N) ++logN;  // 15

    // ws layout: cnt2 | pidx | voxn  ~= 21.4 MB
    uint* cnt2 = (uint*)d_ws;                                        // NB*32*4 = 263168 B
    ushort* pidx = (ushort*)((char*)cnt2 + (size_t)NB * NCHUNK * 4); // NB*32*32*2 = 4.21 MB
    uint* voxn = (uint*)((char*)pidx + (size_t)NB * NCHUNK * CAPC * 2);  // 16.9 MB
    (void)ws_size;

    dim3 bgrid(NCHUNK, B);           // 32 x 8
    bin_kernel<<<bgrid, 256, 0, stream>>>(xyzp, cnt2, pidx, N);
    accum_kernel<<<NB, 256, 0, stream>>>(cnt2, pidx, xyzp, feat, voxn, logN);
    gather_mfma_kernel<<<BN / GPTS, 256, 0, stream>>>(xyzp, voxn, W, bias, out, logN);
}